// Round 1
// baseline (274.895 us; speedup 1.0000x reference)
//
#include <hip/hip_runtime.h>

#define S_LEN 4096
#define DMODEL 768
#define NHEAD 12
#define DHEAD 64

typedef _Float16 half8 __attribute__((ext_vector_type(8)));
typedef float f32x4 __attribute__((ext_vector_type(4)));

__device__ __forceinline__ void glds16(const void* g, void* l) {
  __builtin_amdgcn_global_load_lds((const __attribute__((address_space(1))) unsigned int*)g,
                                   (__attribute__((address_space(3))) unsigned int*)l,
                                   16, 0, 0);
}

// ---------------- fp32 -> fp16 convert (vectorized, 8 elems/thread) ----------------
__global__ void cvt_f32_f16(const float* __restrict__ s, _Float16* __restrict__ d) {
  int i = (blockIdx.x * 256 + threadIdx.x) * 8;
  float4 a = *(const float4*)(s + i);
  float4 b = *(const float4*)(s + i + 4);
  half8 h;
  h[0] = (_Float16)a.x; h[1] = (_Float16)a.y; h[2] = (_Float16)a.z; h[3] = (_Float16)a.w;
  h[4] = (_Float16)b.x; h[5] = (_Float16)b.y; h[6] = (_Float16)b.z; h[7] = (_Float16)b.w;
  *(half8*)(d + i) = h;
}

// ---------------- NT GEMM: C[M,N] = A[M,K] * B[N,K]^T + bias ----------------
// EPI 0: scatter fp16 into Q/K/V [H][S][64] buffers (N=2304)
// EPI 1: fp32 store to out (N=768)
template<int EPI>
__global__ __launch_bounds__(256, 2)
void gemm_nt(const _Float16* __restrict__ A, const _Float16* __restrict__ Bm,
             const float* __restrict__ bias, int M, int N, int K,
             _Float16* __restrict__ qb, _Float16* __restrict__ kb, _Float16* __restrict__ vb,
             float* __restrict__ outp) {
  __shared__ _Float16 Ash[128 * 32];
  __shared__ _Float16 Bsh[128 * 32];
  const int tid = threadIdx.x, lane = tid & 63, wv = tid >> 6;
  const int wr = wv >> 1, wc = wv & 1;
  const int l15 = lane & 15, lg = lane >> 4;
  const int tm = blockIdx.y * 128, tn = blockIdx.x * 128;

  f32x4 acc[4][4] = {};

  const int nk = K >> 5;
  for (int kt = 0; kt < nk; kt++) {
    // stage A tile: 128 rows x 32 halves = 512 16B-chunks -> 2 issues of 256
#pragma unroll
    for (int is = 0; is < 2; is++) {
      int c = is * 256 + tid;
      int r = c >> 2, cc = c & 3;
      glds16(A + (size_t)(tm + r) * K + kt * 32 + cc * 8, &Ash[(is * 256 + wv * 64) * 8]);
    }
#pragma unroll
    for (int is = 0; is < 2; is++) {
      int c = is * 256 + tid;
      int r = c >> 2, cc = c & 3;
      glds16(Bm + (size_t)(tn + r) * K + kt * 32 + cc * 8, &Bsh[(is * 256 + wv * 64) * 8]);
    }
    __syncthreads();

    half8 af[4], bf[4];
#pragma unroll
    for (int m = 0; m < 4; m++)
      af[m] = *(const half8*)&Ash[(wr * 64 + m * 16 + l15) * 32 + lg * 8];
#pragma unroll
    for (int n = 0; n < 4; n++)
      bf[n] = *(const half8*)&Bsh[(wc * 64 + n * 16 + l15) * 32 + lg * 8];
#pragma unroll
    for (int m = 0; m < 4; m++)
#pragma unroll
      for (int n = 0; n < 4; n++)
        acc[m][n] = __builtin_amdgcn_mfma_f32_16x16x32_f16(af[m], bf[n], acc[m][n], 0, 0, 0);
    __syncthreads();
  }

#pragma unroll
  for (int m = 0; m < 4; m++) {
#pragma unroll
    for (int n = 0; n < 4; n++) {
#pragma unroll
      for (int j = 0; j < 4; j++) {
        int gr = tm + wr * 64 + m * 16 + lg * 4 + j;
        int gc = tn + wc * 64 + n * 16 + l15;
        float val = acc[m][n][j] + bias[gc];
        if (EPI == 0) {
          int which = gc / 768;
          int dmcol = gc % 768;
          int head = dmcol >> 6, dh = dmcol & 63;
          _Float16* dst = (which == 0) ? qb : (which == 1) ? kb : vb;
          dst[((size_t)head * S_LEN + gr) * DHEAD + dh] = (_Float16)val;
        } else {
          outp[(size_t)gr * N + gc] = val;
        }
      }
    }
  }
}

// ---------------- V [H][S][64] -> Vt [H][64][S] (LDS tiled transpose) ----------------
__global__ void transpose_v(const _Float16* __restrict__ V, _Float16* __restrict__ Vt) {
  const int h = blockIdx.y;
  const int s0 = blockIdx.x * 64;
  __shared__ _Float16 t[64][72];
  const int tid = threadIdx.x;
#pragma unroll
  for (int i = 0; i < 2; i++) {
    int c = i * 256 + tid;
    int r = c >> 3, cc = c & 7;
    half8 v = *(const half8*)(V + ((size_t)h * S_LEN + s0 + r) * DHEAD + cc * 8);
    *(half8*)&t[r][cc * 8] = v;
  }
  __syncthreads();
#pragma unroll
  for (int i = 0; i < 2; i++) {
    int c = i * 256 + tid;
    int d = c >> 3, sc = c & 7;
    half8 o;
#pragma unroll
    for (int j = 0; j < 8; j++) o[j] = t[sc * 8 + j][d];
    *(half8*)(Vt + ((size_t)h * DHEAD + d) * S_LEN + s0 + sc * 8) = o;
  }
}

// ---------------- attention: softmax over ALL keys, post-softmax causal mask on PV ----------------
__global__ __launch_bounds__(256, 2)
void attn_kernel(const _Float16* __restrict__ Q, const _Float16* __restrict__ K,
                 const _Float16* __restrict__ Vt, _Float16* __restrict__ Y) {
  __shared__ _Float16 Ksh[128 * 64];      // [key][d], chunks XOR-swizzled by key&7
  __shared__ _Float16 Vsh[64 * 128];      // [d][key], chunks XOR-swizzled by d&15
  __shared__ _Float16 Psh[4][32 * 128];   // per-wave P, chunks XOR-swizzled by q&15

  const int tid = threadIdx.x, lane = tid & 63, wv = tid >> 6;
  const int h = blockIdx.y, qt = blockIdx.x;
  const int qb = qt * 128 + wv * 32;
  const int l15 = lane & 15, lg = lane >> 4;

  const _Float16* Qh = Q + (size_t)h * S_LEN * DHEAD;
  const _Float16* Kh = K + (size_t)h * S_LEN * DHEAD;
  const _Float16* Vh = Vt + (size_t)h * DHEAD * S_LEN;

  // Q fragments held in registers for the whole k-loop
  half8 qf[2][2];
#pragma unroll
  for (int i = 0; i < 2; i++)
#pragma unroll
    for (int ks = 0; ks < 2; ks++)
      qf[i][ks] = *(const half8*)(Qh + (size_t)(qb + i * 16 + l15) * DHEAD + ks * 32 + lg * 8);

  f32x4 Oa[2][4] = {};
  f32x4 mrow[2], lrow[2];
#pragma unroll
  for (int i = 0; i < 2; i++)
#pragma unroll
    for (int j = 0; j < 4; j++) { mrow[i][j] = -1e30f; lrow[i][j] = 0.f; }

  for (int kt = 0; kt < 32; kt++) {
    // ---- stage K tile (128x64) and V^T tile (64x128), 1024 chunks each ----
#pragma unroll
    for (int is = 0; is < 4; is++) {
      int c = is * 256 + tid;
      int key = c >> 3, cc = c & 7;
      glds16(Kh + (size_t)(kt * 128 + key) * DHEAD + ((cc ^ (key & 7)) * 8),
             &Ksh[(is * 256 + wv * 64) * 8]);
    }
#pragma unroll
    for (int is = 0; is < 4; is++) {
      int c = is * 256 + tid;
      int d = c >> 4, cc = c & 15;
      glds16(Vh + (size_t)d * S_LEN + kt * 128 + ((cc ^ (d & 15)) * 8),
             &Vsh[(is * 256 + wv * 64) * 8]);
    }
    __syncthreads();

    // ---- scores S = Q K^T (per wave: 32 q-rows x 128 keys) ----
    f32x4 sa[2][8];
#pragma unroll
    for (int i = 0; i < 2; i++)
#pragma unroll
      for (int kf = 0; kf < 8; kf++)
#pragma unroll
        for (int j = 0; j < 4; j++) sa[i][kf][j] = 0.f;
#pragma unroll
    for (int ks = 0; ks < 2; ks++) {
#pragma unroll
      for (int kf = 0; kf < 8; kf++) {
        int key = kf * 16 + l15;
        int cc = ks * 4 + lg;
        half8 kfrag = *(const half8*)&Ksh[key * 64 + ((cc ^ (key & 7)) * 8)];
#pragma unroll
        for (int i = 0; i < 2; i++)
          sa[i][kf] = __builtin_amdgcn_mfma_f32_16x16x32_f16(qf[i][ks], kfrag, sa[i][kf], 0, 0, 0);
      }
    }

    // ---- scale + tile max ----
    f32x4 tmax[2];
#pragma unroll
    for (int i = 0; i < 2; i++)
#pragma unroll
      for (int j = 0; j < 4; j++) tmax[i][j] = -1e30f;
#pragma unroll
    for (int i = 0; i < 2; i++)
#pragma unroll
      for (int kf = 0; kf < 8; kf++)
#pragma unroll
        for (int j = 0; j < 4; j++) {
          sa[i][kf][j] *= 0.125f;
          tmax[i][j] = fmaxf(tmax[i][j], sa[i][kf][j]);
        }
#pragma unroll
    for (int off = 1; off < 16; off <<= 1)
#pragma unroll
      for (int i = 0; i < 2; i++)
#pragma unroll
        for (int j = 0; j < 4; j++)
          tmax[i][j] = fmaxf(tmax[i][j], __shfl_xor(tmax[i][j], off));

    // ---- online softmax update (denominator over ALL keys) ----
    f32x4 mnew[2], alpha[2], tsum[2];
#pragma unroll
    for (int i = 0; i < 2; i++)
#pragma unroll
      for (int j = 0; j < 4; j++) {
        mnew[i][j] = fmaxf(mrow[i][j], tmax[i][j]);
        alpha[i][j] = __expf(mrow[i][j] - mnew[i][j]);
        tsum[i][j] = 0.f;
      }
#pragma unroll
    for (int i = 0; i < 2; i++)
#pragma unroll
      for (int kf = 0; kf < 8; kf++)
#pragma unroll
        for (int j = 0; j < 4; j++) {
          float p = __expf(sa[i][kf][j] - mnew[i][j]);
          sa[i][kf][j] = p;
          tsum[i][j] += p;
        }
#pragma unroll
    for (int off = 1; off < 16; off <<= 1)
#pragma unroll
      for (int i = 0; i < 2; i++)
#pragma unroll
        for (int j = 0; j < 4; j++)
          tsum[i][j] += __shfl_xor(tsum[i][j], off);
#pragma unroll
    for (int i = 0; i < 2; i++)
#pragma unroll
      for (int j = 0; j < 4; j++) {
        lrow[i][j] = lrow[i][j] * alpha[i][j] + tsum[i][j];
        mrow[i][j] = mnew[i][j];
      }
#pragma unroll
    for (int i = 0; i < 2; i++)
#pragma unroll
      for (int df = 0; df < 4; df++)
#pragma unroll
        for (int j = 0; j < 4; j++) Oa[i][df][j] *= alpha[i][j];

    // ---- PV with post-softmax causal mask (skip fully-future tiles) ----
    const int k0 = kt * 128;
    if (k0 <= qb + 31) {
      const bool needmask = (k0 + 127 > qb);
      // write masked P (fp16) into per-wave LDS, chunk-swizzled
#pragma unroll
      for (int i = 0; i < 2; i++)
#pragma unroll
        for (int kf = 0; kf < 8; kf++)
#pragma unroll
          for (int j = 0; j < 4; j++) {
            int qloc = i * 16 + lg * 4 + j;
            int kloc = kf * 16 + l15;
            float p = sa[i][kf][j];
            if (needmask && (k0 + kloc) > (qb + qloc)) p = 0.f;
            int cc = kloc >> 3;
            Psh[wv][qloc * 128 + ((cc ^ (qloc & 15)) * 8) + (kloc & 7)] = (_Float16)p;
          }
      asm volatile("s_waitcnt lgkmcnt(0)" ::: "memory");
      __builtin_amdgcn_sched_barrier(0);

      half8 pa[2][4];
#pragma unroll
      for (int i = 0; i < 2; i++)
#pragma unroll
        for (int ks = 0; ks < 4; ks++) {
          int q = i * 16 + l15;
          int cc = ks * 4 + lg;
          pa[i][ks] = *(const half8*)&Psh[wv][q * 128 + ((cc ^ (q & 15)) * 8)];
        }
#pragma unroll
      for (int df = 0; df < 4; df++) {
#pragma unroll
        for (int ks = 0; ks < 4; ks++) {
          int d = df * 16 + l15;
          int cc = ks * 4 + lg;
          half8 vfrag = *(const half8*)&Vsh[d * 128 + ((cc ^ (d & 15)) * 8)];
#pragma unroll
          for (int i = 0; i < 2; i++)
            Oa[i][df] = __builtin_amdgcn_mfma_f32_16x16x32_f16(pa[i][ks], vfrag, Oa[i][df], 0, 0, 0);
        }
      }
    }
    __syncthreads();
  }

  // ---- epilogue: y[s][h*64+d] = O / l (fp16) ----
#pragma unroll
  for (int i = 0; i < 2; i++)
#pragma unroll
    for (int df = 0; df < 4; df++)
#pragma unroll
      for (int j = 0; j < 4; j++) {
        int row = qb + i * 16 + lg * 4 + j;
        int col = h * 64 + df * 16 + l15;
        Y[(size_t)row * DMODEL + col] = (_Float16)(Oa[i][df][j] / lrow[i][j]);
      }
}

extern "C" void kernel_launch(void* const* d_in, const int* in_sizes, int n_in,
                              void* d_out, int out_size, void* d_ws, size_t ws_size,
                              hipStream_t stream) {
  const float* x    = (const float*)d_in[0];
  const float* Wqkv = (const float*)d_in[1];
  const float* bqkv = (const float*)d_in[2];
  const float* Wout = (const float*)d_in[3];
  const float* bout = (const float*)d_in[4];
  float* out = (float*)d_out;

  size_t off = 0;
  auto alloc = [&](size_t bytes) {
    void* p = (char*)d_ws + off;
    off += (bytes + 255) & ~(size_t)255;
    return p;
  };
  _Float16* xh    = (_Float16*)alloc((size_t)S_LEN * DMODEL * 2);
  _Float16* wqkvh = (_Float16*)alloc((size_t)3 * DMODEL * DMODEL * 2);
  _Float16* wouth = (_Float16*)alloc((size_t)DMODEL * DMODEL * 2);
  _Float16* Qb    = (_Float16*)alloc((size_t)NHEAD * S_LEN * DHEAD * 2);
  _Float16* Kb    = (_Float16*)alloc((size_t)NHEAD * S_LEN * DHEAD * 2);
  _Float16* Vb    = (_Float16*)alloc((size_t)NHEAD * S_LEN * DHEAD * 2);
  _Float16* Vtb   = (_Float16*)alloc((size_t)NHEAD * S_LEN * DHEAD * 2);
  _Float16* Yb    = (_Float16*)alloc((size_t)S_LEN * DMODEL * 2);

  cvt_f32_f16<<<(S_LEN * DMODEL) / 2048, 256, 0, stream>>>(x, xh);
  cvt_f32_f16<<<(3 * DMODEL * DMODEL) / 2048, 256, 0, stream>>>(Wqkv, wqkvh);
  cvt_f32_f16<<<(DMODEL * DMODEL) / 2048, 256, 0, stream>>>(Wout, wouth);

  gemm_nt<0><<<dim3(18, 32), 256, 0, stream>>>(xh, wqkvh, bqkv, S_LEN, 3 * DMODEL, DMODEL,
                                               Qb, Kb, Vb, nullptr);

  transpose_v<<<dim3(S_LEN / 64, NHEAD), 256, 0, stream>>>(Vb, Vtb);

  attn_kernel<<<dim3(S_LEN / 128, NHEAD), 256, 0, stream>>>(Qb, Kb, Vtb, Yb);

  gemm_nt<1><<<dim3(6, 32), 256, 0, stream>>>(Yb, wouth, bout, S_LEN, DMODEL, DMODEL,
                                              nullptr, nullptr, nullptr, out);
}

// Round 2
// 169.660 us; speedup vs baseline: 1.6203x; 1.6203x over previous
//
#include <hip/hip_runtime.h>

#define S_LEN 4096
#define DMODEL 768
#define NHEAD 12
#define DHEAD 64

typedef _Float16 half8 __attribute__((ext_vector_type(8)));
typedef _Float16 half4 __attribute__((ext_vector_type(4)));
typedef float f32x4 __attribute__((ext_vector_type(4)));

#define QSCALE 0.18033688011112042f  /* 0.125 * log2(e) */

__device__ __forceinline__ void glds16(const void* g, void* l) {
  __builtin_amdgcn_global_load_lds((const __attribute__((address_space(1))) unsigned int*)g,
                                   (__attribute__((address_space(3))) unsigned int*)l,
                                   16, 0, 0);
}
__device__ __forceinline__ float fexp2(float x) { return __builtin_amdgcn_exp2f(x); }

// ---------------- fp32 -> fp16 convert ----------------
__global__ void cvt_f32_f16(const float* __restrict__ s, _Float16* __restrict__ d) {
  int i = (blockIdx.x * 256 + threadIdx.x) * 8;
  float4 a = *(const float4*)(s + i);
  float4 b = *(const float4*)(s + i + 4);
  half8 h;
  h[0] = (_Float16)a.x; h[1] = (_Float16)a.y; h[2] = (_Float16)a.z; h[3] = (_Float16)a.w;
  h[4] = (_Float16)b.x; h[5] = (_Float16)b.y; h[6] = (_Float16)b.z; h[7] = (_Float16)b.w;
  *(half8*)(d + i) = h;
}

// ---------------- NT GEMM: C[M,N] = A[M,K] * B[N,K]^T + bias ----------------
// EPI 0: scatter fp16 into Q (pre-scaled) [H][S][64], K [H][S][64], V transposed [H][64][S]
// EPI 1: fp32 store to out (N=768)
template<int EPI>
__global__ __launch_bounds__(256, 2)
void gemm_nt(const _Float16* __restrict__ A, const _Float16* __restrict__ Bm,
             const float* __restrict__ bias, int M, int N, int K,
             _Float16* __restrict__ qb, _Float16* __restrict__ kb, _Float16* __restrict__ vb,
             float* __restrict__ outp) {
  __shared__ _Float16 Ash[128 * 32];
  __shared__ _Float16 Bsh[128 * 32];
  const int tid = threadIdx.x, lane = tid & 63, wv = tid >> 6;
  const int wr = wv >> 1, wc = wv & 1;
  const int l15 = lane & 15, lg = lane >> 4;
  const int tm = blockIdx.y * 128, tn = blockIdx.x * 128;

  f32x4 acc[4][4] = {};

  const int nk = K >> 5;
  for (int kt = 0; kt < nk; kt++) {
#pragma unroll
    for (int is = 0; is < 2; is++) {
      int c = is * 256 + tid;
      int r = c >> 2, cc = c & 3;
      glds16(A + (size_t)(tm + r) * K + kt * 32 + cc * 8, &Ash[(is * 256 + wv * 64) * 8]);
    }
#pragma unroll
    for (int is = 0; is < 2; is++) {
      int c = is * 256 + tid;
      int r = c >> 2, cc = c & 3;
      glds16(Bm + (size_t)(tn + r) * K + kt * 32 + cc * 8, &Bsh[(is * 256 + wv * 64) * 8]);
    }
    __syncthreads();

    half8 af[4], bf[4];
#pragma unroll
    for (int m = 0; m < 4; m++)
      af[m] = *(const half8*)&Ash[(wr * 64 + m * 16 + l15) * 32 + lg * 8];
#pragma unroll
    for (int n = 0; n < 4; n++)
      bf[n] = *(const half8*)&Bsh[(wc * 64 + n * 16 + l15) * 32 + lg * 8];
#pragma unroll
    for (int m = 0; m < 4; m++)
#pragma unroll
      for (int n = 0; n < 4; n++)
        acc[m][n] = __builtin_amdgcn_mfma_f32_16x16x32_f16(af[m], bf[n], acc[m][n], 0, 0, 0);
    __syncthreads();
  }

#pragma unroll
  for (int m = 0; m < 4; m++) {
#pragma unroll
    for (int n = 0; n < 4; n++) {
#pragma unroll
      for (int j = 0; j < 4; j++) {
        int gr = tm + wr * 64 + m * 16 + lg * 4 + j;
        int gc = tn + wc * 64 + n * 16 + l15;
        float val = acc[m][n][j] + bias[gc];
        if (EPI == 0) {
          int which = gc / 768;
          int dmcol = gc % 768;
          int head = dmcol >> 6, dh = dmcol & 63;
          if (which == 0) {
            qb[((size_t)head * S_LEN + gr) * DHEAD + dh] = (_Float16)(val * QSCALE);
          } else if (which == 1) {
            kb[((size_t)head * S_LEN + gr) * DHEAD + dh] = (_Float16)val;
          } else {
            // store V transposed: Vt[h][dh][s]
            vb[((size_t)head * DHEAD + dh) * S_LEN + gr] = (_Float16)val;
          }
        } else {
          outp[(size_t)gr * N + gc] = val;
        }
      }
    }
  }
}

// ---------------- attention (split-K flash, swapped-operand MFMA) ----------------
// grid: (32 q-tiles x 2 ksplits, 12 heads); block: 4 waves, 32 q-rows each.
// Softmax denominator over ALL keys of the split; post-softmax causal mask on PV.
// Partial output O^T-accumulated, stored f32 with per-row (m, l) in log2 units.
__global__ __launch_bounds__(256, 3)
void attn_kernel(const _Float16* __restrict__ Q, const _Float16* __restrict__ K,
                 const _Float16* __restrict__ Vt,
                 float* __restrict__ Op, float* __restrict__ Ml) {
  __shared__ _Float16 Ksh[2][64 * 64];   // [key][d], 16B chunks swizzled by key&7
  __shared__ _Float16 Vsh[2][64 * 64];   // [d][key], 16B chunks swizzled by d&7
  __shared__ _Float16 Psh[4][32 * 64];   // per-wave [q][k], 16B chunks swizzled by q&7

  const int tid = threadIdx.x, lane = tid & 63, wv = tid >> 6;
  const int l15 = lane & 15, lg = lane >> 4;
  const int qt = blockIdx.x & 31, sp = blockIdx.x >> 5;
  const int h = blockIdx.y;
  const int qg0 = qt * 128 + wv * 32;
  const int qmax_blk = qt * 128 + 127;
  const int k0base = sp * 2048;

  const _Float16* Qh = Q + (size_t)h * S_LEN * DHEAD;
  const _Float16* Kh = K + (size_t)h * S_LEN * DHEAD;
  const _Float16* Vh = Vt + (size_t)h * DHEAD * S_LEN;

  // Q fragments (pre-scaled), B-operand layout: rows = q
  half8 qf[2][2];
#pragma unroll
  for (int i = 0; i < 2; i++)
#pragma unroll
    for (int ks = 0; ks < 2; ks++)
      qf[i][ks] = *(const half8*)(Qh + (size_t)(qg0 + i * 16 + l15) * DHEAD + ks * 32 + lg * 8);

  float m[2] = {-1e30f, -1e30f}, l[2] = {0.f, 0.f};
  f32x4 Oa[2][4] = {};

  auto stageK = [&](int t, int b) {
    const int k0 = k0base + t * 64;
#pragma unroll
    for (int is = 0; is < 2; is++) {
      int c = is * 256 + tid;
      int r = c >> 3, cc = c & 7;
      glds16(Kh + (size_t)(k0 + r) * DHEAD + ((cc ^ (r & 7)) * 8),
             &Ksh[b][(is * 256 + wv * 64) * 8]);
    }
  };
  auto stageV = [&](int t, int b) {
    const int k0 = k0base + t * 64;
#pragma unroll
    for (int is = 0; is < 2; is++) {
      int c = is * 256 + tid;
      int d = c >> 3, cc = c & 7;
      glds16(Vh + (size_t)d * S_LEN + k0 + ((cc ^ (d & 7)) * 8),
             &Vsh[b][(is * 256 + wv * 64) * 8]);
    }
  };

  stageK(0, 0);
  if (k0base <= qmax_blk) stageV(0, 0);
  __syncthreads();

  for (int t = 0; t < 32; t++) {
    const int cur = t & 1, nb = cur ^ 1;
    const int k0g = k0base + t * 64;
    // prefetch next tile into other buffer (drained by end-of-iter barrier)
    if (t < 31) {
      stageK(t + 1, nb);
      if (k0base + (t + 1) * 64 <= qmax_blk) stageV(t + 1, nb);
    }

    // ---- S^T = K Q^T : per-lane q = l15, key = kf*16 + lg*4 + j ----
    f32x4 sa[2][4] = {};
#pragma unroll
    for (int ks = 0; ks < 2; ks++) {
#pragma unroll
      for (int kf = 0; kf < 4; kf++) {
        int key = kf * 16 + l15;
        half8 kfr = *(const half8*)&Ksh[cur][key * 64 + (((ks * 4 + lg) ^ (key & 7)) * 8)];
#pragma unroll
        for (int i = 0; i < 2; i++)
          sa[i][kf] = __builtin_amdgcn_mfma_f32_16x16x32_f16(kfr, qf[i][ks], sa[i][kf], 0, 0, 0);
      }
    }

    // ---- online softmax: per-lane scalar state (row q = i*16 + l15) ----
#pragma unroll
    for (int i = 0; i < 2; i++) {
      float tmax = -1e30f;
#pragma unroll
      for (int kf = 0; kf < 4; kf++)
#pragma unroll
        for (int j = 0; j < 4; j++) tmax = fmaxf(tmax, sa[i][kf][j]);
      tmax = fmaxf(tmax, __shfl_xor(tmax, 16));
      tmax = fmaxf(tmax, __shfl_xor(tmax, 32));
      float mn = fmaxf(m[i], tmax);
      float al = fexp2(m[i] - mn);
      float ts = 0.f;
#pragma unroll
      for (int kf = 0; kf < 4; kf++)
#pragma unroll
        for (int j = 0; j < 4; j++) {
          float p = fexp2(sa[i][kf][j] - mn);
          sa[i][kf][j] = p;
          ts += p;
        }
      ts += __shfl_xor(ts, 16);
      ts += __shfl_xor(ts, 32);
      l[i] = l[i] * al + ts;
      m[i] = mn;
#pragma unroll
      for (int df = 0; df < 4; df++) Oa[i][df] *= al;
    }

    // ---- PV with post-softmax causal mask (skip fully-future tiles) ----
    if (k0g <= qg0 + 31) {
      // packed masked P -> per-wave LDS (b64 writes, 16B-chunk XOR swizzle)
#pragma unroll
      for (int i = 0; i < 2; i++) {
        int qloc = i * 16 + l15, qg = qg0 + i * 16 + l15;
#pragma unroll
        for (int kf = 0; kf < 4; kf++) {
          int kb = k0g + kf * 16 + lg * 4;
          half4 pk;
#pragma unroll
          for (int j = 0; j < 4; j++)
            pk[j] = (kb + j > qg) ? (_Float16)0.f : (_Float16)sa[i][kf][j];
          *(half4*)&Psh[wv][qloc * 64 + (((kf * 2 + (lg >> 1)) ^ (qloc & 7)) << 3) + (lg & 1) * 4] = pk;
        }
      }
      half8 pa[2][2];
#pragma unroll
      for (int i = 0; i < 2; i++) {
        int qloc = i * 16 + l15;
#pragma unroll
        for (int ks = 0; ks < 2; ks++)
          pa[i][ks] = *(const half8*)&Psh[wv][qloc * 64 + (((ks * 4 + lg) ^ (qloc & 7)) << 3)];
      }
      // O^T += V^T P^T : per-lane q = l15, d = df*16 + lg*4 + j
#pragma unroll
      for (int ks = 0; ks < 2; ks++) {
#pragma unroll
        for (int df = 0; df < 4; df++) {
          int d = df * 16 + l15;
          half8 vf = *(const half8*)&Vsh[cur][d * 64 + (((ks * 4 + lg) ^ (d & 7)) * 8)];
#pragma unroll
          for (int i = 0; i < 2; i++)
            Oa[i][df] = __builtin_amdgcn_mfma_f32_16x16x32_f16(vf, pa[i][ks], Oa[i][df], 0, 0, 0);
        }
      }
    }
    __syncthreads();
  }

  // ---- epilogue: partial O (f32) + (m, l) ----
  const size_t obase = (size_t)(sp * NHEAD + h) * S_LEN * DHEAD;
#pragma unroll
  for (int i = 0; i < 2; i++) {
    int qg = qg0 + i * 16 + l15;
#pragma unroll
    for (int df = 0; df < 4; df++)
      *(f32x4*)&Op[obase + (size_t)qg * DHEAD + df * 16 + lg * 4] = Oa[i][df];
    if (lg == 0) {
      float2 v = make_float2(m[i], l[i]);
      *(float2*)&Ml[((size_t)(sp * NHEAD + h) * S_LEN + qg) * 2] = v;
    }
  }
}

// ---------------- combine the two k-splits ----------------
__global__ void combine(const float* __restrict__ Op, const float* __restrict__ Ml,
                        _Float16* __restrict__ Y) {
  int idx = blockIdx.x * 256 + threadIdx.x;
  int d = (idx & 7) * 8;
  int qh = idx >> 3;
  int q = qh & (S_LEN - 1);
  int h = qh >> 12;
  float2 ml0 = *(const float2*)&Ml[((size_t)h * S_LEN + q) * 2];
  float2 ml1 = *(const float2*)&Ml[((size_t)(NHEAD + h) * S_LEN + q) * 2];
  float M = fmaxf(ml0.x, ml1.x);
  float w0 = fexp2(ml0.x - M), w1 = fexp2(ml1.x - M);
  float inv = 1.f / (w0 * ml0.y + w1 * ml1.y);
  w0 *= inv; w1 *= inv;
  size_t b0 = ((size_t)h * S_LEN + q) * DHEAD + d;
  size_t b1 = ((size_t)(NHEAD + h) * S_LEN + q) * DHEAD + d;
  half8 o;
#pragma unroll
  for (int j = 0; j < 8; j += 4) {
    f32x4 a = *(const f32x4*)&Op[b0 + j];
    f32x4 b = *(const f32x4*)&Op[b1 + j];
#pragma unroll
    for (int jj = 0; jj < 4; jj++) o[j + jj] = (_Float16)(a[jj] * w0 + b[jj] * w1);
  }
  *(half8*)(Y + (size_t)q * DMODEL + h * 64 + d) = o;
}

extern "C" void kernel_launch(void* const* d_in, const int* in_sizes, int n_in,
                              void* d_out, int out_size, void* d_ws, size_t ws_size,
                              hipStream_t stream) {
  const float* x    = (const float*)d_in[0];
  const float* Wqkv = (const float*)d_in[1];
  const float* bqkv = (const float*)d_in[2];
  const float* Wout = (const float*)d_in[3];
  const float* bout = (const float*)d_in[4];
  float* out = (float*)d_out;

  size_t off = 0;
  auto alloc = [&](size_t bytes) {
    void* p = (char*)d_ws + off;
    off += (bytes + 255) & ~(size_t)255;
    return p;
  };
  _Float16* xh    = (_Float16*)alloc((size_t)S_LEN * DMODEL * 2);
  _Float16* wqkvh = (_Float16*)alloc((size_t)3 * DMODEL * DMODEL * 2);
  _Float16* wouth = (_Float16*)alloc((size_t)DMODEL * DMODEL * 2);
  _Float16* Qb    = (_Float16*)alloc((size_t)NHEAD * S_LEN * DHEAD * 2);
  _Float16* Kb    = (_Float16*)alloc((size_t)NHEAD * S_LEN * DHEAD * 2);
  _Float16* Vb    = (_Float16*)alloc((size_t)NHEAD * S_LEN * DHEAD * 2);  // transposed [H][64][S]
  _Float16* Yb    = (_Float16*)alloc((size_t)S_LEN * DMODEL * 2);
  float*    Opb   = (float*)alloc((size_t)2 * NHEAD * S_LEN * DHEAD * 4);
  float*    Mlb   = (float*)alloc((size_t)2 * NHEAD * S_LEN * 2 * 4);

  cvt_f32_f16<<<(S_LEN * DMODEL) / 2048, 256, 0, stream>>>(x, xh);
  cvt_f32_f16<<<(3 * DMODEL * DMODEL) / 2048, 256, 0, stream>>>(Wqkv, wqkvh);
  cvt_f32_f16<<<(DMODEL * DMODEL) / 2048, 256, 0, stream>>>(Wout, wouth);

  gemm_nt<0><<<dim3(18, 32), 256, 0, stream>>>(xh, wqkvh, bqkv, S_LEN, 3 * DMODEL, DMODEL,
                                               Qb, Kb, Vb, nullptr);

  attn_kernel<<<dim3(64, NHEAD), 256, 0, stream>>>(Qb, Kb, Vb, Opb, Mlb);

  combine<<<(NHEAD * S_LEN * 8) / 256, 256, 0, stream>>>(Opb, Mlb, Yb);

  gemm_nt<1><<<dim3(6, 32), 256, 0, stream>>>(Yb, wouth, bout, S_LEN, DMODEL, DMODEL,
                                              nullptr, nullptr, nullptr, out);
}